// Round 3
// baseline (137.809 us; speedup 1.0000x reference)
//
#include <hip/hip_runtime.h>

// Haar wavelet decomposition of channel 0 of (32,3,512,512) fp32.
// Output (32,4,256,256): bands ll,lh,hl,hh.
//
// ILP-max variant: each thread handles 8 input col-pairs (two groups of
// 4) from one input row-pair -> 8 float4 loads issued back-to-back
// (8KB in flight per wave, 2x the previous version), then 8 float4
// non-temporal stores. Grid halves to 1024 blocks. Total bytes
// unchanged (67MB r+w). Tests whether the ~19us kernel slice is
// latency/ramp-limited (faster) or fixed-overhead-limited (neutral =>
// roofline: the ~118us of harness poison-fills dominate the
// measurement).
//
// NOTE: ext_vector elements are not addressable (&v.x is a compile
// error) -- use v[k] subscripting instead.

typedef float f4 __attribute__((ext_vector_type(4)));

__device__ __forceinline__ void haar4(const f4 A0, const f4 A1,
                                      const f4 C0, const f4 C1,
                                      f4& ll, f4& lh, f4& hl, f4& hh) {
    // Even row cols: A0={a0,b0,a1,b1}, A1={a2,b2,a3,b3}; odd row: C0,C1.
    float a[4]  = {A0.x, A0.z, A1.x, A1.z};
    float bb[4] = {A0.y, A0.w, A1.y, A1.w};
    float c[4]  = {C0.x, C0.z, C1.x, C1.z};
    float d[4]  = {C0.y, C0.w, C1.y, C1.w};
#pragma unroll
    for (int k = 0; k < 4; ++k) {
        float s_ab = a[k] + bb[k], d_ab = a[k] - bb[k];
        float s_cd = c[k] + d[k],  d_cd = c[k] - d[k];
        ll[k] = (s_ab + s_cd) * 0.5f;
        lh[k] = (s_ab - s_cd) * 0.5f;
        hl[k] = (d_ab + d_cd) * 0.5f;
        hh[k] = (d_ab - d_cd) * 0.5f;
    }
}

__global__ __launch_bounds__(256) void haar_kernel(const float* __restrict__ x,
                                                   float* __restrict__ out) {
    int tid = blockIdx.x * blockDim.x + threadIdx.x;  // total 32*256*32 = 1<<18
    int l = tid & 31;             // col group: input cols 8l.. and 256+8l..
    int i = (tid >> 5) & 255;     // output row
    int b = tid >> 13;            // batch

    const float* r0 = x + (size_t)b * (3 * 512 * 512) + (2 * i) * 512 + 8 * l;
    const float* r1 = r0 + 512;

    // 8 loads issued back-to-back: 128B/thread in flight.
    const f4 A0 = *(const f4*)(r0);
    const f4 A1 = *(const f4*)(r0 + 4);
    const f4 C0 = *(const f4*)(r1);
    const f4 C1 = *(const f4*)(r1 + 4);
    const f4 B0 = *(const f4*)(r0 + 256);
    const f4 B1 = *(const f4*)(r0 + 260);
    const f4 D0 = *(const f4*)(r1 + 256);
    const f4 D1 = *(const f4*)(r1 + 260);

    f4 ll0, lh0, hl0, hh0, ll1, lh1, hl1, hh1;
    haar4(A0, A1, C0, C1, ll0, lh0, hl0, hh0);
    haar4(B0, B1, D0, D1, ll1, lh1, hl1, hh1);

    // out[b][band][i][col], band stride 256*256 = 65536 floats.
    float* o = out + (size_t)b * 262144 + i * 256 + 4 * l;
    __builtin_nontemporal_store(ll0, (f4*)(o));
    __builtin_nontemporal_store(lh0, (f4*)(o + 65536));
    __builtin_nontemporal_store(hl0, (f4*)(o + 131072));
    __builtin_nontemporal_store(hh0, (f4*)(o + 196608));
    __builtin_nontemporal_store(ll1, (f4*)(o + 128));
    __builtin_nontemporal_store(lh1, (f4*)(o + 65536 + 128));
    __builtin_nontemporal_store(hl1, (f4*)(o + 131072 + 128));
    __builtin_nontemporal_store(hh1, (f4*)(o + 196608 + 128));
}

extern "C" void kernel_launch(void* const* d_in, const int* in_sizes, int n_in,
                              void* d_out, int out_size, void* d_ws, size_t ws_size,
                              hipStream_t stream) {
    const float* x = (const float*)d_in[0];
    float* out = (float*)d_out;
    haar_kernel<<<1024, 256, 0, stream>>>(x, out);
}